// Round 8
// baseline (88.545 us; speedup 1.0000x reference)
//
#include <hip/hip_runtime.h>

#define D    32       // feature dim (fixed)
#define BLK  256      // threads per block (4 waves)
#define NCH  16       // j-chunks per batch -> grid.y (2048 blocks total)
#define STJ  64       // j-rows per LDS stage (4 MFMA tiles; one per wave)
#define LOG2E 1.44269504088896340736f

typedef short short8  __attribute__((ext_vector_type(8)));
typedef float floatx4 __attribute__((ext_vector_type(4)));
typedef float v2f     __attribute__((ext_vector_type(2)));

__device__ __forceinline__ short f2bf(float v) {       // fp32 -> bf16 (RTNE-ish)
    union { float f; unsigned u; } x; x.f = v;
    unsigned r = x.u + 0x7fffu + ((x.u >> 16) & 1u);
    return (short)(r >> 16);
}
__device__ __forceinline__ float bf2f(short h) {
    union { float f; unsigned u; } x;
    x.u = ((unsigned)(unsigned short)h) << 16;
    return x.f;
}
__device__ __forceinline__ float fast_exp2(float x) {
#if __has_builtin(__builtin_amdgcn_exp2f)
    return __builtin_amdgcn_exp2f(x);
#else
    return exp2f(x);
#endif
}

// ---------------------------------------------------------------------------
// Kernel P (4-way parallel: one thread per row-octet (r,q), 32768 threads).
// Builds fragment-major MFMA operands (identical math/layout to R7, which
// verified absmax 0.0):
//   Spatial MFMA operands sAj/sBi: x scaled by s2l=sqrt(2*log2e) split h/l/ll,
//   xn=log2e*|x|^2 split 3-way (j) / 2-way (i); one MFMA yields the complete
//   log2 spatial logit (i-side truncation cancels in the softmax ratio).
//   Feature fAh/fAl (f2) and fBh/fBl (f1): scaled by s2l, h/l split.
//   Norms reduced across the 4 octet-threads via shfl_xor(1|2).
// Fragment-major: row n (t=n/16, m=n%16), octet q -> arr[(t*64+m+16q)*8 ..+8).
// ---------------------------------------------------------------------------
__global__ __launch_bounds__(BLK) void precompute_kernel(
    const float* __restrict__ points,
    const float* __restrict__ fea1,
    const float* __restrict__ fea2,
    short* __restrict__ sAj, short* __restrict__ sBi,
    short* __restrict__ fAh, short* __restrict__ fAl,
    short* __restrict__ fBh, short* __restrict__ fBl,
    float* __restrict__ fn2, float* __restrict__ nf1,
    float* __restrict__ acc, float* __restrict__ out,
    int BN, int Bsz)
{
    const int g = blockIdx.x * BLK + threadIdx.x;
    const int r = g >> 2, q = g & 3;
    if (r >= BN) return;
    if (g < Bsz) out[g] = 0.0f;
    acc[q * BN + r] = 0.0f;
    if (q == 0) acc[4 * BN + r] = 0.0f;

    const float s2l = sqrtf(2.0f * LOG2E);
    const int t = r >> 4, m = r & 15;
    const size_t fb = ((size_t)t * 64 + m + 16*q) * 8;   // this thread's octet

    // ---- spatial (each octet-thread computes the small split, writes its q)
    float x0 = points[3*r+0] * 20.f;
    float x1 = points[3*r+1] * 20.f;
    float x2 = points[3*r+2] * 20.f;
    float xn = (x0*x0 + x1*x1 + x2*x2) * LOG2E;
    float xs[3] = {x0*s2l, x1*s2l, x2*s2l};
    short h[3], l[3], ll[3];
#pragma unroll
    for (int c = 0; c < 3; ++c) {
        h[c] = f2bf(xs[c]);
        float rm = xs[c] - bf2f(h[c]);
        l[c] = f2bf(rm);
        rm -= bf2f(l[c]);
        ll[c] = f2bf(rm);
    }
    short xnh = f2bf(xn);
    float rn = xn - bf2f(xnh);
    short xnm = f2bf(rn);
    rn -= bf2f(xnm);
    short xnl = f2bf(rn);
    const short N1 = (short)0xBF80;   // bf16 -1.0

    short8 aq, bq;
    if (q == 0) {
        aq = (short8){h[0],h[1],h[2], l[0],l[1],l[2], ll[0],ll[1]};
        bq = (short8){h[0],h[1],h[2], h[0],h[1],h[2], h[0],h[1]};
    } else if (q == 1) {
        aq = (short8){ll[2], h[0],h[1],h[2], l[0],l[1],l[2], ll[0]};
        bq = (short8){h[2], l[0],l[1],l[2], l[0],l[1],l[2], l[0]};
    } else if (q == 2) {
        aq = (short8){ll[1],ll[2], h[0],h[1],h[2], l[0],l[1],l[2]};
        bq = (short8){l[1],l[2], ll[0],ll[1],ll[2], ll[0],ll[1],ll[2]};
    } else {
        aq = (short8){ll[0],ll[1],ll[2], xnh,xnm,xnl, N1,N1};
        bq = (short8){ll[0],ll[1],ll[2], N1,N1,N1, xnh,xnm};
    }
    *(short8*)&sAj[fb] = aq;
    *(short8*)&sBi[fb] = bq;

    // ---- features: this thread's 8 elements of f1 and f2 ----
    const float* p1 = fea1 + (size_t)r * D + q*8;
    const float* p2 = fea2 + (size_t)r * D + q*8;
    float4 a0 = *(const float4*)(p1);
    float4 a1 = *(const float4*)(p1 + 4);
    float e1[8] = {a0.x,a0.y,a0.z,a0.w,a1.x,a1.y,a1.z,a1.w};
    float n1 = 0.f, n2 = 0.f;
    short8 hh, llv;
#pragma unroll
    for (int k = 0; k < 8; ++k) {
        n1 = fmaf(e1[k], e1[k], n1);
        float v = e1[k] * s2l;
        short hv = f2bf(v);
        hh[k] = hv;
        llv[k] = f2bf(v - bf2f(hv));
    }
    *(short8*)&fBh[fb] = hh;
    *(short8*)&fBl[fb] = llv;

    float4 b0 = *(const float4*)(p2);
    float4 b1 = *(const float4*)(p2 + 4);
    float e2[8] = {b0.x,b0.y,b0.z,b0.w,b1.x,b1.y,b1.z,b1.w};
#pragma unroll
    for (int k = 0; k < 8; ++k) {
        n2 = fmaf(e2[k], e2[k], n2);
        float v = e2[k] * s2l;
        short hv = f2bf(v);
        hh[k] = hv;
        llv[k] = f2bf(v - bf2f(hv));
    }
    *(short8*)&fAh[fb] = hh;
    *(short8*)&fAl[fb] = llv;

    // ---- norm reduce across the 4 octet-threads (same wave) ----
    n1 += __shfl_xor(n1, 1); n1 += __shfl_xor(n1, 2);
    n2 += __shfl_xor(n2, 1); n2 += __shfl_xor(n2, 2);
    if (q == 0) {
        nf1[r] = n1 * LOG2E;
        fn2[r] = n2 * LOG2E;
    }
}

// ---------------------------------------------------------------------------
// Kernel A: pair loop. Block = 64 i-rows (4 i-tiles) x JCH j's; 4 waves.
// EACH WAVE OWNS ONE j-TILE per stage and sweeps ALL 4 i-tiles, so the
// 4 LDS reads per j-tile (As,Ah,Al,fnq) feed 4 tile-computations (R7: 1) --
// LDS-pipe cost drops 4x. Stages are register-prefetch double-buffered.
// Per 16x16 tile: 1 spatial MFMA (complete logit) + 3 feature MFMAs seeded
// with -nf_i - fn_j, then per-pair just 2 exp2 + 3 accumulates.
// ---------------------------------------------------------------------------
__global__ __launch_bounds__(BLK) void pair_kernel(
    const short* __restrict__ sAj,
    const short* __restrict__ fAh,
    const short* __restrict__ fAl,
    const short* __restrict__ sBi,
    const short* __restrict__ fBh,
    const short* __restrict__ fBl,
    const float* __restrict__ fn2,
    const float* __restrict__ nf1,
    float* __restrict__ acc,
    int N, int BN)
{
    __shared__ __align__(16) short lAs[STJ * D];  // 4 KB spatial A frags
    __shared__ __align__(16) short lAh[STJ * D];  // 4 KB feature A hi
    __shared__ __align__(16) short lAl[STJ * D];  // 4 KB feature A lo
    __shared__ __align__(16) float lFn[STJ];      // 256 B fp32 fn2

    const int tid  = threadIdx.x;
    const int lane = tid & 63;
    const int wv   = tid >> 6;
    const int m    = lane & 15;        // i-offset (C col)
    const int q    = lane >> 4;        // j-quad (C row group)

    const int ibpb   = N >> 6;         // i-blocks per batch
    const int b      = blockIdx.x / ibpb;
    const int itile0 = blockIdx.x * 4; // first of this block's 4 i-tiles
    const int JCH    = N / NCH;
    const int jc0    = blockIdx.y * JCH;

    // ---- persistent i-side fragments for 4 i-tiles ----
    short8 Bs[4], Bfh[4], Bfl[4];
    float nfin[4];
#pragma unroll
    for (int it = 0; it < 4; ++it) {
        const size_t ti = ((size_t)(itile0 + it) * 64 + lane) * 8;
        Bs[it]  = *(const short8*)&sBi[ti];
        Bfh[it] = *(const short8*)&fBh[ti];
        Bfl[it] = *(const short8*)&fBl[ti];
        nfin[it] = -nf1[(itile0 + it) * 16 + m];
    }

    v2f  sAB[4] = {{0.f,0.f},{0.f,0.f},{0.f,0.f},{0.f,0.f}};
    v2f  s2 [4] = {{0.f,0.f},{0.f,0.f},{0.f,0.f},{0.f,0.f}};
    float sab[4] = {0.f,0.f,0.f,0.f};

    const int tjbase = (b * N + jc0) >> 4;
    const uint4* gAs = (const uint4*)(sAj + (size_t)tjbase * 512);
    const uint4* gAh = (const uint4*)(fAh + (size_t)tjbase * 512);
    const uint4* gAl = (const uint4*)(fAl + (size_t)tjbase * 512);
    const float* gFn = fn2 + (size_t)b * N + jc0;

    // prefetch stage 0 (64 j-rows = 256 uint4 per array)
    uint4 pA = gAs[tid], pH = gAh[tid], pL = gAl[tid];
    float pF = (tid < STJ) ? gFn[tid] : 0.f;

    for (int s0 = 0; s0 < JCH; s0 += STJ) {
        ((uint4*)lAs)[tid] = pA;
        ((uint4*)lAh)[tid] = pH;
        ((uint4*)lAl)[tid] = pL;
        if (tid < STJ) lFn[tid] = pF;
        __syncthreads();

        const int sn = s0 + STJ;
        if (sn < JCH) {                 // prefetch next stage during compute
            const int to = sn * 4;
            pA = gAs[to + tid]; pH = gAh[to + tid]; pL = gAl[to + tid];
            pF = (tid < STJ) ? gFn[sn + tid] : 0.f;
        }

        // ---- wave wv owns j-tile wv of this stage; sweep 4 i-tiles ----
        const short8 As = *(const short8*)&lAs[(wv*64 + lane)*8];
        const short8 Ah = *(const short8*)&lAh[(wv*64 + lane)*8];
        const short8 Al = *(const short8*)&lAl[(wv*64 + lane)*8];
        const floatx4 fnq = *(const floatx4*)&lFn[wv*16 + q*4];

#pragma unroll
        for (int it = 0; it < 4; ++it) {
            floatx4 cs = {0.f, 0.f, 0.f, 0.f};
            cs = __builtin_amdgcn_mfma_f32_16x16x32_bf16(As, Bs[it], cs, 0, 0, 0);

            floatx4 cf = {nfin[it] - fnq[0], nfin[it] - fnq[1],
                          nfin[it] - fnq[2], nfin[it] - fnq[3]};
            cf = __builtin_amdgcn_mfma_f32_16x16x32_bf16(Ah, Bfh[it], cf, 0, 0, 0);
            cf = __builtin_amdgcn_mfma_f32_16x16x32_bf16(Ah, Bfl[it], cf, 0, 0, 0);
            cf = __builtin_amdgcn_mfma_f32_16x16x32_bf16(Al, Bfh[it], cf, 0, 0, 0);

#pragma unroll
            for (int r = 0; r < 4; ++r) {
                float ea = fast_exp2(cs[r]);
                float eb = fast_exp2(cf[r]);
                v2f e = {ea, eb};
                sAB[it] += e;                                   // v_pk_add_f32
                s2[it]   = __builtin_elementwise_fma(e, e, s2[it]);
                sab[it]  = fmaf(ea, eb, sab[it]);
            }
        }
        __syncthreads();
    }

    // ---- reduce the 4 j-quads (lanes sharing lane&15), then atomics ----
#pragma unroll
    for (int it = 0; it < 4; ++it) {
        float vA = sAB[it].x, vB = sAB[it].y;
        float v2a = s2[it].x, v2b = s2[it].y, vab = sab[it];
        vA  += __shfl_xor(vA, 16);  vA  += __shfl_xor(vA, 32);
        vB  += __shfl_xor(vB, 16);  vB  += __shfl_xor(vB, 32);
        v2a += __shfl_xor(v2a, 16); v2a += __shfl_xor(v2a, 32);
        v2b += __shfl_xor(v2b, 16); v2b += __shfl_xor(v2b, 32);
        vab += __shfl_xor(vab, 16); vab += __shfl_xor(vab, 32);
        if (lane < 16) {
            int row = (itile0 + it) * 16 + lane;
            atomicAdd(&acc[0*BN + row], vA);
            atomicAdd(&acc[1*BN + row], v2a);
            atomicAdd(&acc[2*BN + row], vB);
            atomicAdd(&acc[3*BN + row], v2b);
            atomicAdd(&acc[4*BN + row], vab);
        }
    }
}

// ---------------------------------------------------------------------------
// Kernel B: combine per-row sums, weight, reduce into out[b] (out zeroed by P).
//   out[b] = sum_i w_i * ( S2a/A^2 - 2*Sab/(A*B) + S2b/B^2 )
// ---------------------------------------------------------------------------
__global__ __launch_bounds__(BLK) void finalize_kernel(
    const float* __restrict__ acc,
    const float* __restrict__ weights,
    float* __restrict__ out,
    int N, int BN)
{
    int row = blockIdx.x * BLK + threadIdx.x;
    int b   = (blockIdx.x * BLK) / N;

    float A   = acc[0*BN + row];
    float S2a = acc[1*BN + row];
    float Bt  = acc[2*BN + row];
    float S2b = acc[3*BN + row];
    float Sab = acc[4*BN + row];
    float invA = 1.0f / A;
    float invB = 1.0f / Bt;
    float val  = S2a*invA*invA - 2.0f*Sab*invA*invB + S2b*invB*invB;
    float sum  = weights[row] * val;

    __shared__ float red[BLK/64];
    for (int off = 32; off > 0; off >>= 1)
        sum += __shfl_down(sum, off);
    if ((threadIdx.x & 63) == 0) red[threadIdx.x >> 6] = sum;
    __syncthreads();
    if (threadIdx.x == 0) {
        float s = 0.f;
#pragma unroll
        for (int w = 0; w < BLK/64; ++w) s += red[w];
        atomicAdd(&out[b], s);
    }
}

// ---------------------------------------------------------------------------
extern "C" void kernel_launch(void* const* d_in, const int* in_sizes, int n_in,
                              void* d_out, int out_size, void* d_ws, size_t ws_size,
                              hipStream_t stream) {
    const float* points  = (const float*)d_in[0];
    const float* fea1    = (const float*)d_in[1];
    const float* fea2    = (const float*)d_in[2];
    const float* weights = (const float*)d_in[3];
    float* out = (float*)d_out;

    int B  = out_size;          // 2
    int BN = in_sizes[3];       // B*N = 8192
    int N  = BN / B;            // 4096

    // workspace: acc | sAj | sBi | fAh | fAl | fBh | fBl | fn2 | nf1
    float* acc = (float*)d_ws;
    char*  p   = (char*)d_ws + (size_t)5 * BN * 4;
    short* sAj = (short*)p; p += (size_t)BN * 64;
    short* sBi = (short*)p; p += (size_t)BN * 64;
    short* fAh = (short*)p; p += (size_t)BN * 64;
    short* fAl = (short*)p; p += (size_t)BN * 64;
    short* fBh = (short*)p; p += (size_t)BN * 64;
    short* fBl = (short*)p; p += (size_t)BN * 64;
    float* fn2 = (float*)p; p += (size_t)BN * 4;
    float* nf1 = (float*)p;

    precompute_kernel<<<dim3((BN * 4 + BLK - 1) / BLK), dim3(BLK), 0, stream>>>(
        points, fea1, fea2, sAj, sBi, fAh, fAl, fBh, fBl, fn2, nf1,
        acc, out, BN, B);

    dim3 grid(BN / 64, NCH);    // 128 x 16 = 2048 blocks
    pair_kernel<<<grid, dim3(BLK), 0, stream>>>(
        sAj, fAh, fAl, sBi, fBh, fBl, fn2, nf1, acc, N, BN);

    finalize_kernel<<<dim3(BN / BLK), dim3(BLK), 0, stream>>>(acc, weights, out, N, BN);
}

// Round 9
// 84.817 us; speedup vs baseline: 1.0440x; 1.0440x over previous
//
#include <hip/hip_runtime.h>

#define D    32       // feature dim (fixed)
#define BLK  256      // threads per block (4 waves, 64 i-rows per block)
#define NCH  16       // j-chunks per batch -> grid.y
#define SJ   128      // j-rows staged in LDS per stage (8 MFMA tiles)

#define LOG2E 1.44269504088896340736f

typedef short  short8  __attribute__((ext_vector_type(8)));
typedef float  floatx4 __attribute__((ext_vector_type(4)));
typedef float  v2f     __attribute__((ext_vector_type(2)));

__device__ __forceinline__ short f2bf(float v) {       // fp32 -> bf16 (RTNE-ish)
    union { float f; unsigned u; } x; x.f = v;
    unsigned r = x.u + 0x7fffu + ((x.u >> 16) & 1u);
    return (short)(r >> 16);
}
__device__ __forceinline__ float bf2f(short h) {
    union { float f; unsigned u; } x;
    x.u = ((unsigned)(unsigned short)h) << 16;
    return x.f;
}
__device__ __forceinline__ float fast_exp2(float x) {
#if __has_builtin(__builtin_amdgcn_exp2f)
    return __builtin_amdgcn_exp2f(x);
#else
    return exp2f(x);
#endif
}

// ---------------------------------------------------------------------------
// Kernel P: per-row precompute + zero-init + global bf16 hi/lo split of fea2
// stored FRAGMENT-MAJOR: for row n (tile t=n/16, m=n%16), k-octet q, the
// 8 bf16 go to slot l=m+16q of tile t:  gX[(t*64 + l)*8 .. +8).
// This makes both the pair-kernel staging copy and the per-lane A-fragment
// ds_read lane-contiguous (zero bank conflicts, minimal LDS cycles).
//   xp[r]  = (20*px, 20*py, 20*pz, log2e*|20*p|^2)
//   f1n[r] = log2e*|fea1_r|^2,  f2n[r] = log2e*|fea2_r|^2
// ---------------------------------------------------------------------------
__global__ __launch_bounds__(BLK) void precompute_kernel(
    const float* __restrict__ points,
    const float* __restrict__ fea1,
    const float* __restrict__ fea2,
    float4* __restrict__ xp,
    float* __restrict__ f1n,
    float* __restrict__ f2n,
    short* __restrict__ f2hi,
    short* __restrict__ f2lo,
    float* __restrict__ acc,
    float* __restrict__ out,
    int BN, int Bsz)
{
    int r = blockIdx.x * BLK + threadIdx.x;
    if (r < Bsz) out[r] = 0.0f;
    if (r >= BN) return;
#pragma unroll
    for (int s = 0; s < 5; ++s) acc[s * BN + r] = 0.0f;

    const float s20 = 20.0f;                 // 1/SIGMA
    float x = points[3*r+0] * s20;
    float y = points[3*r+1] * s20;
    float z = points[3*r+2] * s20;
    float4 v; v.x = x; v.y = y; v.z = z;
    v.w = (x*x + y*y + z*z) * LOG2E;
    xp[r] = v;

    // f1 norm
    const float4* p1 = (const float4*)(fea1 + (size_t)r * D);
    float n1 = 0.f;
#pragma unroll
    for (int k = 0; k < D/4; ++k) {
        float4 a = p1[k];
        n1 = fmaf(a.x,a.x, fmaf(a.y,a.y, fmaf(a.z,a.z, fmaf(a.w,a.w, n1))));
    }
    f1n[r] = n1 * LOG2E;

    // f2: norm + hi/lo split, scattered fragment-major
    const int t = r >> 4;                    // global 16-row tile id
    const int m = r & 15;
    const float* p2 = fea2 + (size_t)r * D;
    float n2 = 0.f;
#pragma unroll
    for (int q = 0; q < 4; ++q) {
        float4 v0 = *(const float4*)(p2 + q*8);
        float4 v1 = *(const float4*)(p2 + q*8 + 4);
        float e[8] = {v0.x,v0.y,v0.z,v0.w,v1.x,v1.y,v1.z,v1.w};
        short8 h, l;
#pragma unroll
        for (int k = 0; k < 8; ++k) {
            n2 = fmaf(e[k], e[k], n2);
            short hh = f2bf(e[k]);
            h[k] = hh;
            l[k] = f2bf(e[k] - bf2f(hh));
        }
        size_t off = ((size_t)t * 64 + m + 16*q) * 8;
        *(short8*)&f2hi[off] = h;
        *(short8*)&f2lo[off] = l;
    }
    f2n[r] = n2 * LOG2E;
}

// ---------------------------------------------------------------------------
// Kernel A: pair loop with MFMA feature dot (split-bf16: hi*hi+hi*lo+lo*hi).
//   Block = 4 waves x 16 i-rows = 64 rows, x one j-chunk of N/NCH.
//   f2 hi/lo arrive pre-split, fragment-major -> staging is a pure uint4
//   copy (contiguous->contiguous); A-fragment reads are lane-contiguous
//   ds_read_b128 (structural-minimum LDS cycles, zero conflicts).
//   Spatial logit per-pair fp32 VALU (cancellation-sensitive, keeps absmax 0).
//   [Session note: this exact kernel measured 86.0 us total -- the session
//    best.  Five structurally different pair variants (R4-R8) all land in
//    86-91 us: pair is pinned at ~30 us by dependent-chain latency, and the
//    remaining ~56 us is harness fill (268 MB poison @ 82% HBM peak) +
//    restores + dispatch gaps.  Reverted to best.]
// ---------------------------------------------------------------------------
__global__ __launch_bounds__(BLK) void pair_kernel(
    const float* __restrict__ fea1,
    const short* __restrict__ f2hi,
    const short* __restrict__ f2lo,
    const float4* __restrict__ xp,
    const float* __restrict__ f1n,
    const float* __restrict__ f2n,
    float* __restrict__ acc,
    int N, int BN)
{
    __shared__ __align__(16) short sHi[SJ * D];   // 8 KB, fragment-major
    __shared__ __align__(16) short sLo[SJ * D];   // 8 KB
    __shared__ float4 sXJ[SJ];                    // 2 KB
    __shared__ float  sFN[SJ];                    // 512 B

    const int tid  = threadIdx.x;
    const int lane = tid & 63;
    const int wv   = tid >> 6;
    const int m    = lane & 15;        // i-offset (B n-index / C col)
    const int q    = lane >> 4;        // k-octet / j-quad

    const int ibpb  = N / 64;          // i-blocks per batch
    const int b     = blockIdx.x / ibpb;
    const int ibase = blockIdx.x * 64 + wv * 16;
    const int JCH   = N / NCH;
    const int jc0   = blockIdx.y * JCH;

    // ---- B fragments: f1 rows of this wave's 16 i's, split hi/lo ----
    const float* f1p = fea1 + (size_t)(ibase + m) * D + q * 8;
    float4 bv0 = *(const float4*)(f1p);
    float4 bv1 = *(const float4*)(f1p + 4);
    float bf[8] = {bv0.x,bv0.y,bv0.z,bv0.w,bv1.x,bv1.y,bv1.z,bv1.w};
    short8 Bhi, Blo;
#pragma unroll
    for (int k = 0; k < 8; ++k) {
        short h = f2bf(bf[k]);
        Bhi[k] = h;
        Blo[k] = f2bf(bf[k] - bf2f(h));
    }

    const float L2 = 2.0f * LOG2E;
    float4 xi = xp[ibase + m];
    float xix = xi.x * L2, xiy = xi.y * L2, xiz = xi.z * L2;
    float mxiw = -xi.w;
    float nfi  = -f1n[ibase + m];      // -log2e*|f1_i|^2

    v2f sAB = {0.f, 0.f};              // (sum e^a, sum e^b)
    v2f s2  = {0.f, 0.f};              // (sum e^2a, sum e^2b)
    float sab = 0.f;                   // sum e^a e^b

    const short*  gHi  = f2hi + ((size_t)(b * N + jc0) >> 4) * 512;
    const short*  gLo  = f2lo + ((size_t)(b * N + jc0) >> 4) * 512;
    const float4* xpb  = xp  + (size_t)b * N + jc0;
    const float*  f2nb = f2n + (size_t)b * N + jc0;

    for (int s = 0; s < JCH; s += SJ) {
        // ---- stage: pure contiguous copy (8 KB hi + 8 KB lo) ----
        const uint4* srcH = (const uint4*)(gHi + (size_t)(s >> 4) * 512);
        const uint4* srcL = (const uint4*)(gLo + (size_t)(s >> 4) * 512);
        uint4* dstH = (uint4*)sHi;
        uint4* dstL = (uint4*)sLo;
        dstH[tid]       = srcH[tid];
        dstH[tid + 256] = srcH[tid + 256];
        dstL[tid]       = srcL[tid];
        dstL[tid + 256] = srcL[tid + 256];
        if (tid < SJ) {
            sXJ[tid] = xpb[s + tid];
            sFN[tid] = f2nb[s + tid];
        }
        __syncthreads();

        // ---- compute: 8 16x16 pair tiles ----
#pragma unroll 2
        for (int jt8 = 0; jt8 < SJ/16; ++jt8) {
            const short8 Ahi = *(const short8*)&sHi[(jt8 * 64 + lane) * 8];
            const short8 Alo = *(const short8*)&sLo[(jt8 * 64 + lane) * 8];
            floatx4 c = {0.f, 0.f, 0.f, 0.f};
            c = __builtin_amdgcn_mfma_f32_16x16x32_bf16(Ahi, Bhi, c, 0, 0, 0);
            c = __builtin_amdgcn_mfma_f32_16x16x32_bf16(Ahi, Blo, c, 0, 0, 0);
            c = __builtin_amdgcn_mfma_f32_16x16x32_bf16(Alo, Bhi, c, 0, 0, 0);
#pragma unroll
            for (int r = 0; r < 4; ++r) {
                int jl = jt8 * 16 + q * 4 + r;
                float4 xj = sXJ[jl];
                float bL = fmaf(c[r], L2, nfi - sFN[jl]);       // log2 feature
                float aL = fmaf(xiz, xj.z,
                             fmaf(xiy, xj.y,
                              fmaf(xix, xj.x, mxiw))) - xj.w;   // log2 spatial
                float ea = fast_exp2(aL);
                float eb = fast_exp2(bL);
                v2f e = {ea, eb};
                sAB += e;                                   // v_pk_add_f32
                s2   = __builtin_elementwise_fma(e, e, s2); // v_pk_fma_f32
                sab  = fmaf(ea, eb, sab);
            }
        }
        __syncthreads();
    }

    // ---- reduce the 4 j-quads (lanes sharing lane&15) ----
    float vA = sAB.x, vB = sAB.y, v2a = s2.x, v2b = s2.y, vab = sab;
    vA  += __shfl_xor(vA, 16);  vA  += __shfl_xor(vA, 32);
    vB  += __shfl_xor(vB, 16);  vB  += __shfl_xor(vB, 32);
    v2a += __shfl_xor(v2a, 16); v2a += __shfl_xor(v2a, 32);
    v2b += __shfl_xor(v2b, 16); v2b += __shfl_xor(v2b, 32);
    vab += __shfl_xor(vab, 16); vab += __shfl_xor(vab, 32);

    if (lane < 16) {
        int row = ibase + lane;
        atomicAdd(&acc[0*BN + row], vA);
        atomicAdd(&acc[1*BN + row], v2a);
        atomicAdd(&acc[2*BN + row], vB);
        atomicAdd(&acc[3*BN + row], v2b);
        atomicAdd(&acc[4*BN + row], vab);
    }
}

// ---------------------------------------------------------------------------
// Kernel B: combine per-row sums, weight, reduce into out[b] (out zeroed by P).
//   out[b] = sum_i w_i * ( S2a/A^2 - 2*Sab/(A*B) + S2b/B^2 )
// ---------------------------------------------------------------------------
__global__ __launch_bounds__(BLK) void finalize_kernel(
    const float* __restrict__ acc,
    const float* __restrict__ weights,
    float* __restrict__ out,
    int N, int BN)
{
    int row = blockIdx.x * BLK + threadIdx.x;
    int b   = (blockIdx.x * BLK) / N;

    float A   = acc[0*BN + row];
    float S2a = acc[1*BN + row];
    float Bt  = acc[2*BN + row];
    float S2b = acc[3*BN + row];
    float Sab = acc[4*BN + row];
    float invA = 1.0f / A;
    float invB = 1.0f / Bt;
    float val  = S2a*invA*invA - 2.0f*Sab*invA*invB + S2b*invB*invB;
    float sum  = weights[row] * val;

    __shared__ float red[BLK/64];
    for (int off = 32; off > 0; off >>= 1)
        sum += __shfl_down(sum, off);
    if ((threadIdx.x & 63) == 0) red[threadIdx.x >> 6] = sum;
    __syncthreads();
    if (threadIdx.x == 0) {
        float s = 0.f;
#pragma unroll
        for (int w = 0; w < BLK/64; ++w) s += red[w];
        atomicAdd(&out[b], s);
    }
}

// ---------------------------------------------------------------------------
extern "C" void kernel_launch(void* const* d_in, const int* in_sizes, int n_in,
                              void* d_out, int out_size, void* d_ws, size_t ws_size,
                              hipStream_t stream) {
    const float* points  = (const float*)d_in[0];
    const float* fea1    = (const float*)d_in[1];
    const float* fea2    = (const float*)d_in[2];
    const float* weights = (const float*)d_in[3];
    float* out = (float*)d_out;

    int B  = out_size;          // 2
    int BN = in_sizes[3];       // B*N = 8192
    int N  = BN / B;            // 4096

    // workspace (bytes):
    //   acc  : 5*BN*4   @ 0
    //   xp   : 4*BN*4   @ 5*BN*4
    //   f2n  : BN*4     @ 9*BN*4
    //   f1n  : BN*4     @ 10*BN*4
    //   f2hi : BN*D*2   @ 11*BN*4
    //   f2lo : BN*D*2
    float*  acc  = (float*)d_ws;
    float4* xp   = (float4*)((char*)d_ws + (size_t)5  * BN * 4);
    float*  f2n  = (float*)((char*)d_ws + (size_t)9  * BN * 4);
    float*  f1n  = (float*)((char*)d_ws + (size_t)10 * BN * 4);
    short*  f2hi = (short*)((char*)d_ws + (size_t)11 * BN * 4);
    short*  f2lo = f2hi + (size_t)BN * D;

    precompute_kernel<<<dim3((BN + BLK - 1) / BLK), dim3(BLK), 0, stream>>>(
        points, fea1, fea2, xp, f1n, f2n, f2hi, f2lo, acc, out, BN, B);

    dim3 grid(BN / 64, NCH);    // 128 x 16 = 2048 blocks (8 blocks/CU)
    pair_kernel<<<grid, dim3(BLK), 0, stream>>>(
        fea1, f2hi, f2lo, xp, f1n, f2n, acc, N, BN);

    finalize_kernel<<<dim3(BN / BLK), dim3(BLK), 0, stream>>>(acc, weights, out, N, BN);
}